// Round 7
// baseline (415.771 us; speedup 1.0000x reference)
//
#include <hip/hip_runtime.h>
#include <math.h>

#define H 18
#define NS 65536
#define AD 4
#define ITERS 6
#define DELTA 16.0f
#define NWG 256
#define WGS 256
#define CAPB 256      // per-block segment capacity == WGS => cannot overflow
#define SCAP 1024

__device__ __forceinline__ unsigned encf(float f) {
    unsigned u = __float_as_uint(f);
    return (u & 0x80000000u) ? ~u : (u | 0x80000000u);
}
__device__ __forceinline__ float decf(unsigned u) {
    return __uint_as_float((u & 0x80000000u) ? (u & 0x7FFFFFFFu) : ~u);
}
__device__ __forceinline__ float clamp4f(float x) { return fminf(fmaxf(x, -4.0f), 4.0f); }
// descending u64 order == value desc, then index asc (matches top_k tie-break)
__device__ __forceinline__ unsigned long long packkey(float v, unsigned idx) {
    return ((unsigned long long)encf(v) << 32) | (unsigned long long)(~idx);
}

// Lightweight device-wide barrier (2-level arrive tree + flag spin).
// bar: 64 uints per instance, zeroed by hipMemsetAsync before launch.
__device__ __forceinline__ void gbar(unsigned* bar, int k, int wg) {
    unsigned* b = bar + k * 64;
    __syncthreads();
    if (threadIdx.x == 0) {
        __builtin_amdgcn_fence(__ATOMIC_RELEASE, "agent");
        unsigned o = __hip_atomic_fetch_add(&b[wg & 15], 1u, __ATOMIC_ACQ_REL, __HIP_MEMORY_SCOPE_AGENT);
        if (o == 15u) {
            unsigned o2 = __hip_atomic_fetch_add(&b[16], 1u, __ATOMIC_ACQ_REL, __HIP_MEMORY_SCOPE_AGENT);
            if (o2 == 15u)
                __hip_atomic_store(&b[17], 1u, __ATOMIC_RELEASE, __HIP_MEMORY_SCOPE_AGENT);
        }
        while (__hip_atomic_load(&b[17], __ATOMIC_ACQUIRE, __HIP_MEMORY_SCOPE_AGENT) == 0u)
            __builtin_amdgcn_s_sleep(2);
    }
    __syncthreads();
    __builtin_amdgcn_fence(__ATOMIC_ACQUIRE, "agent");
}

__global__ void __launch_bounds__(WGS) k_mppi(
        const float* __restrict__ pi, const float* __restrict__ noise,
        const float* __restrict__ target, float* __restrict__ out,
        unsigned* __restrict__ bar,
        float* __restrict__ bmaxp, float* __restrict__ bmaxc,
        unsigned* __restrict__ cntp, unsigned* __restrict__ cntc,
        float* __restrict__ pvals, unsigned* __restrict__ pidx,
        float* __restrict__ cvals, unsigned* __restrict__ cidx) {
    __shared__ float tgt[H * AD], mnL[H * AD];
    __shared__ float wmx[4];
    __shared__ unsigned long long skey[SCAP];
    __shared__ float buf[64 * 73];
    __shared__ float w[64];
    __shared__ unsigned s_cnt, s_fcnt;
    __shared__ float s_S;

    const int tid = threadIdx.x;
    const int wg = blockIdx.x;
    const int lane = tid & 63;
    const int wid = tid >> 6;
    const int n = wg * WGS + tid;

    if (tid < H * AD) {
        tgt[tid] = target[tid];
        mnL[tid] = pi[(size_t)(tid >> 2) * NS * AD + (tid & 3)];  // pi[:,0,:]
    }
    if (tid == 0) s_cnt = 0u;
    __syncthreads();

    // ---- pi candidate values (iteration-invariant)
    const float4* pi4 = (const float4*)pi;
    float acc = 0.f;
#pragma unroll
    for (int h = 0; h < H; ++h) {
        float4 p = pi4[(size_t)h * NS + n];
        float c;
        c = p.x - tgt[h*4+0]; acc += c*c;
        c = p.y - tgt[h*4+1]; acc += c*c;
        c = p.z - tgt[h*4+2]; acc += c*c;
        c = p.w - tgt[h*4+3]; acc += c*c;
    }
    const float vpi = -acc;
    {
        float m = vpi;
        for (int off = 32; off; off >>= 1) m = fmaxf(m, __shfl_xor(m, off));
        if (lane == 0) wmx[wid] = m;
    }
    __syncthreads();
    {
        const float bmax = fmaxf(fmaxf(wmx[0], wmx[1]), fmaxf(wmx[2], wmx[3]));
        if (tid == 0) bmaxp[wg] = bmax;
        if (vpi >= bmax - DELTA) {
            unsigned p = atomicAdd(&s_cnt, 1u);
            pvals[wg * CAPB + p] = vpi; pidx[wg * CAPB + p] = (unsigned)n;
        }
    }
    __syncthreads();
    if (tid == 0) cntp[wg] = s_cnt;

    float scale = 0.5f;   // iter0: STD*std=0.5*1; iters>=1: 0.5*2=1.0 (clip(std,18,2)==2)
    for (int i = 0; i < ITERS; ++i) {
        // ---- phase A: cem values for iter i
        const float4* nz4 = (const float4*)noise + (size_t)i * H * NS;
        float a2 = 0.f;
#pragma unroll
        for (int h = 0; h < H; ++h) {
            float4 x = nz4[(size_t)h * NS + n];
            float c;
            c = clamp4f(mnL[h*4+0] + scale * x.x) - tgt[h*4+0]; a2 += c*c;
            c = clamp4f(mnL[h*4+1] + scale * x.y) - tgt[h*4+1]; a2 += c*c;
            c = clamp4f(mnL[h*4+2] + scale * x.z) - tgt[h*4+2]; a2 += c*c;
            c = clamp4f(mnL[h*4+3] + scale * x.w) - tgt[h*4+3]; a2 += c*c;
        }
        const float vc = -a2;
        float m2 = vc;
        for (int off = 32; off; off >>= 1) m2 = fmaxf(m2, __shfl_xor(m2, off));
        __syncthreads();               // prior wmx/s_cnt uses complete
        if (tid == 0) s_cnt = 0u;
        if (lane == 0) wmx[wid] = m2;
        __syncthreads();
        {
            const float bmax2 = fmaxf(fmaxf(wmx[0], wmx[1]), fmaxf(wmx[2], wmx[3]));
            if (tid == 0) bmaxc[(size_t)i * NWG + wg] = bmax2;
            if (vc >= bmax2 - DELTA) {
                unsigned p = atomicAdd(&s_cnt, 1u);
                size_t slot = (size_t)i * NWG * CAPB + (size_t)wg * CAPB + p;
                cvals[slot] = vc; cidx[slot] = (unsigned)(NS + n);
            }
        }
        __syncthreads();
        if (tid == 0) cntc[(size_t)i * NWG + wg] = s_cnt;

        gbar(bar, i, wg);              // pushes of iter i globally visible

        if (i == ITERS - 1) break;

        // ---- phase B (redundant in every block; all compute identical mnL)
        {
            float g = fmaxf(bmaxp[tid], bmaxc[(size_t)i * NWG + tid]);  // tid<256==NWG
            for (int off = 32; off; off >>= 1) g = fmaxf(g, __shfl_xor(g, off));
            if (lane == 0) wmx[wid] = g;
        }
        if (tid == 0) s_fcnt = 0u;
        __syncthreads();
        const float gmax = fmaxf(fmaxf(wmx[0], wmx[1]), fmaxf(wmx[2], wmx[3]));
        const float thr = gmax - DELTA;
        // filter: thread t scans segment t (NWG==WGS)
        {
            unsigned c = cntp[tid];
            for (unsigned k = 0; k < c; ++k) {
                float val = pvals[tid * CAPB + k];
                if (val >= thr) {
                    unsigned p = atomicAdd(&s_fcnt, 1u);
                    if (p < SCAP) skey[p] = packkey(val, pidx[tid * CAPB + k]);
                }
            }
            c = cntc[(size_t)i * NWG + tid];
            const size_t sb = (size_t)i * NWG * CAPB + (size_t)tid * CAPB;
            for (unsigned k = 0; k < c; ++k) {
                float val = cvals[sb + k];
                if (val >= thr) {
                    unsigned p = atomicAdd(&s_fcnt, 1u);
                    if (p < SCAP) skey[p] = packkey(val, cidx[sb + k]);
                }
            }
        }
        __syncthreads();
        unsigned fc = s_fcnt; if (fc > SCAP) fc = SCAP;
        if (fc > 64u) {   // exact top-64 via bitonic on packed keys
            unsigned P2 = 128; while (P2 < fc) P2 <<= 1;
            for (unsigned k = fc + tid; k < P2; k += WGS) skey[k] = 0ull;
            __syncthreads();
            for (unsigned kk = 2; kk <= P2; kk <<= 1) {
                for (unsigned j = kk >> 1; j; j >>= 1) {
                    for (unsigned x = tid; x < P2; x += WGS) {
                        unsigned l = x ^ j;
                        if (l > x) {
                            unsigned long long k0 = skey[x], k1 = skey[l];
                            bool desc = ((x & kk) == 0);
                            if (desc ? (k0 < k1) : (k0 > k1)) { skey[x] = k1; skey[l] = k0; }
                        }
                    }
                    __syncthreads();
                }
            }
        }
        const int E = (fc < 64u) ? (int)fc : 64;
        if (tid < 64) {
            float we = (tid < E) ? expf(decf((unsigned)(skey[tid] >> 32)) - gmax) : 0.0f;
            w[tid] = we;
            float s = we;
            for (int off = 32; off; off >>= 1) s += __shfl_xor(s, off);
            if (tid == 0) s_S = s;
        }
        __syncthreads();
        const float invS = 1.0f / (s_S * (1.0f + 1e-9f));
        // gather elite actions: thread (e,a), batched 18 loads
        {
            const int e = tid >> 2, aa = tid & 3;
            float av[H];
            unsigned idx = (e < E) ? (unsigned)~(unsigned)(skey[e] & 0xFFFFFFFFull) : 0u;
            if (e < E) {
                if (idx < NS) {
#pragma unroll
                    for (int h = 0; h < H; ++h)
                        av[h] = pi[(size_t)h * NS * AD + (size_t)idx * AD + aa];
                } else {
                    const unsigned mm = idx - NS;
                    const float* nzi = noise + (size_t)i * H * NS * AD;
#pragma unroll
                    for (int h = 0; h < H; ++h)
                        av[h] = clamp4f(mnL[h*4+aa] + scale * nzi[(size_t)h * NS * AD + (size_t)mm * AD + aa]);
                }
            } else {
#pragma unroll
                for (int h = 0; h < H; ++h) av[h] = 0.0f;
            }
            const float we = (e < E) ? w[e] : 0.0f;
#pragma unroll
            for (int h = 0; h < H; ++h) buf[e * 73 + h * 4 + aa] = we * av[h];
        }
        __syncthreads();
        if (tid < H * AD) {
            float s = 0.f;
#pragma unroll 8
            for (int e = 0; e < 64; ++e) s += buf[e * 73 + tid];
            mnL[tid] = 0.1f * mnL[tid] + 0.9f * (s * invS);
        }
        __syncthreads();
        scale = 1.0f;
    }

    // ---- final: block 0 takes exact argmax over (pi-list ∪ cem5-list)
    if (wg == 0) {
        unsigned long long bk = 0ull;
        {
            unsigned c = cntp[tid];
            for (unsigned k = 0; k < c; ++k) {
                unsigned long long key = packkey(pvals[tid * CAPB + k], pidx[tid * CAPB + k]);
                if (key > bk) bk = key;
            }
            c = cntc[(size_t)5 * NWG + tid];
            const size_t sb = (size_t)5 * NWG * CAPB + (size_t)tid * CAPB;
            for (unsigned k = 0; k < c; ++k) {
                unsigned long long key = packkey(cvals[sb + k], cidx[sb + k]);
                if (key > bk) bk = key;
            }
        }
        for (int off = 32; off; off >>= 1) {
            unsigned long long ok = __shfl_xor(bk, off);
            if (ok > bk) bk = ok;
        }
        if (lane == 0) skey[wid] = bk;
        __syncthreads();
        if (tid == 0) {
            unsigned long long b0 = skey[0];
            for (int q = 1; q < 4; ++q) if (skey[q] > b0) b0 = skey[q];
            skey[0] = b0;
        }
        __syncthreads();
        const unsigned idx = (unsigned)~(unsigned)(skey[0] & 0xFFFFFFFFull);
        if (tid < H * AD) {
            const int h = tid >> 2, aa = tid & 3;
            float o;
            if (idx < NS) o = pi[(size_t)h * NS * AD + (size_t)idx * AD + aa];
            else o = clamp4f(mnL[tid] + 1.0f * noise[(size_t)5 * H * NS * AD + (size_t)h * NS * AD + (size_t)(idx - NS) * AD + aa]);
            out[tid] = o;
        }
    }
}

extern "C" void kernel_launch(void* const* d_in, const int* in_sizes, int n_in,
                              void* d_out, int out_size, void* d_ws, size_t ws_size,
                              hipStream_t stream) {
    const float* pi     = (const float*)d_in[0];
    const float* noise  = (const float*)d_in[1];
    const float* target = (const float*)d_in[2];
    float* out = (float*)d_out;

    unsigned* bar   = (unsigned*)d_ws;                        // 6*64 uints (memset)
    float* bmaxp    = (float*)(bar + 6 * 64);                 // NWG
    float* bmaxc    = bmaxp + NWG;                            // 6*NWG
    unsigned* cntp  = (unsigned*)(bmaxc + ITERS * NWG);       // NWG
    unsigned* cntc  = cntp + NWG;                             // 6*NWG
    float* pvals    = (float*)(cntc + ITERS * NWG);           // NWG*CAPB
    unsigned* pidx  = (unsigned*)(pvals + NWG * CAPB);        // NWG*CAPB
    float* cvals    = (float*)(pidx + NWG * CAPB);            // 6*NWG*CAPB
    unsigned* cidx  = (unsigned*)(cvals + (size_t)ITERS * NWG * CAPB);

    (void)hipMemsetAsync(bar, 0, 6 * 64 * sizeof(unsigned), stream);

    void* args[] = {(void*)&pi, (void*)&noise, (void*)&target, (void*)&out,
                    (void*)&bar, (void*)&bmaxp, (void*)&bmaxc, (void*)&cntp,
                    (void*)&cntc, (void*)&pvals, (void*)&pidx, (void*)&cvals,
                    (void*)&cidx};
    (void)hipLaunchCooperativeKernel((void*)k_mppi, dim3(NWG), dim3(WGS), args, 0, stream);
}

// Round 8
// 361.210 us; speedup vs baseline: 1.1511x; 1.1511x over previous
//
#include <hip/hip_runtime.h>
#include <math.h>

#define H 18
#define NS 65536
#define AD 4
#define ITERS 6
#define DELTA 16.0f
#define NWG 256
#define WGS 256
#define CAPB 256      // per-block segment capacity == WGS => cannot overflow
#define SCAP 1024

__device__ __forceinline__ unsigned encf(float f) {
    unsigned u = __float_as_uint(f);
    return (u & 0x80000000u) ? ~u : (u | 0x80000000u);
}
__device__ __forceinline__ float decf(unsigned u) {
    return __uint_as_float((u & 0x80000000u) ? (u & 0x7FFFFFFFu) : ~u);
}
__device__ __forceinline__ float clamp4f(float x) { return fminf(fmaxf(x, -4.0f), 4.0f); }
// descending u64 order == value desc, then index asc (matches top_k tie-break)
__device__ __forceinline__ unsigned long long packkey(float v, unsigned idx) {
    return ((unsigned long long)encf(v) << 32) | (unsigned long long)(~idx);
}

// Lightweight device-wide barrier (2-level arrive tree + flag spin).
// bar: 64 uints per instance, zeroed by hipMemsetAsync before launch.
// KEY CHANGE vs R7: polls are RELAXED (plain sc1 load to L3 — no buffer_inv
// per poll); ONE acquire fence after the flag flips. Counter RMWs are RELAXED
// too — the explicit release fence before them orders the data, and the flag
// store is control-dependent on the RMW result so it cannot issue early.
__device__ __forceinline__ void gbar(unsigned* bar, int k, int wg) {
    unsigned* b = bar + k * 64;
    __syncthreads();
    if (threadIdx.x == 0) {
        __builtin_amdgcn_fence(__ATOMIC_RELEASE, "agent");
        unsigned o = __hip_atomic_fetch_add(&b[wg & 15], 1u, __ATOMIC_RELAXED, __HIP_MEMORY_SCOPE_AGENT);
        if (o == 15u) {
            unsigned o2 = __hip_atomic_fetch_add(&b[16], 1u, __ATOMIC_RELAXED, __HIP_MEMORY_SCOPE_AGENT);
            if (o2 == 15u)
                __hip_atomic_store(&b[17], 1u, __ATOMIC_RELAXED, __HIP_MEMORY_SCOPE_AGENT);
        }
        while (__hip_atomic_load(&b[17], __ATOMIC_RELAXED, __HIP_MEMORY_SCOPE_AGENT) == 0u)
            __builtin_amdgcn_s_sleep(2);
    }
    __syncthreads();
    __builtin_amdgcn_fence(__ATOMIC_ACQUIRE, "agent");
}

__global__ void __launch_bounds__(WGS) k_mppi(
        const float* __restrict__ pi, const float* __restrict__ noise,
        const float* __restrict__ target, float* __restrict__ out,
        unsigned* __restrict__ bar,
        float* __restrict__ bmaxp, float* __restrict__ bmaxc,
        unsigned* __restrict__ cntp, unsigned* __restrict__ cntc,
        float* __restrict__ pvals, unsigned* __restrict__ pidx,
        float* __restrict__ cvals, unsigned* __restrict__ cidx) {
    __shared__ float tgt[H * AD], mnL[H * AD];
    __shared__ float wmx[4];
    __shared__ unsigned long long skey[SCAP];
    __shared__ float buf[64 * 73];
    __shared__ float w[64];
    __shared__ unsigned s_cnt, s_fcnt;
    __shared__ float s_S;

    const int tid = threadIdx.x;
    const int wg = blockIdx.x;
    const int lane = tid & 63;
    const int wid = tid >> 6;
    const int n = wg * WGS + tid;

    if (tid < H * AD) {
        tgt[tid] = target[tid];
        mnL[tid] = pi[(size_t)(tid >> 2) * NS * AD + (tid & 3)];  // pi[:,0,:]
    }
    if (tid == 0) s_cnt = 0u;
    __syncthreads();

    // ---- pi candidate values (iteration-invariant)
    const float4* pi4 = (const float4*)pi;
    float acc = 0.f;
#pragma unroll
    for (int h = 0; h < H; ++h) {
        float4 p = pi4[(size_t)h * NS + n];
        float c;
        c = p.x - tgt[h*4+0]; acc += c*c;
        c = p.y - tgt[h*4+1]; acc += c*c;
        c = p.z - tgt[h*4+2]; acc += c*c;
        c = p.w - tgt[h*4+3]; acc += c*c;
    }
    const float vpi = -acc;
    {
        float m = vpi;
        for (int off = 32; off; off >>= 1) m = fmaxf(m, __shfl_xor(m, off));
        if (lane == 0) wmx[wid] = m;
    }
    __syncthreads();
    {
        const float bmax = fmaxf(fmaxf(wmx[0], wmx[1]), fmaxf(wmx[2], wmx[3]));
        if (tid == 0) bmaxp[wg] = bmax;
        if (vpi >= bmax - DELTA) {
            unsigned p = atomicAdd(&s_cnt, 1u);
            pvals[wg * CAPB + p] = vpi; pidx[wg * CAPB + p] = (unsigned)n;
        }
    }
    __syncthreads();
    if (tid == 0) cntp[wg] = s_cnt;

    float scale = 0.5f;   // iter0: STD*std=0.5*1; iters>=1: 0.5*2=1.0 (clip(std,18,2)==2)
    for (int i = 0; i < ITERS; ++i) {
        // ---- phase A: cem values for iter i
        const float4* nz4 = (const float4*)noise + (size_t)i * H * NS;
        float a2 = 0.f;
#pragma unroll
        for (int h = 0; h < H; ++h) {
            float4 x = nz4[(size_t)h * NS + n];
            float c;
            c = clamp4f(mnL[h*4+0] + scale * x.x) - tgt[h*4+0]; a2 += c*c;
            c = clamp4f(mnL[h*4+1] + scale * x.y) - tgt[h*4+1]; a2 += c*c;
            c = clamp4f(mnL[h*4+2] + scale * x.z) - tgt[h*4+2]; a2 += c*c;
            c = clamp4f(mnL[h*4+3] + scale * x.w) - tgt[h*4+3]; a2 += c*c;
        }
        const float vc = -a2;
        float m2 = vc;
        for (int off = 32; off; off >>= 1) m2 = fmaxf(m2, __shfl_xor(m2, off));
        __syncthreads();               // prior wmx/s_cnt uses complete
        if (tid == 0) s_cnt = 0u;
        if (lane == 0) wmx[wid] = m2;
        __syncthreads();
        {
            const float bmax2 = fmaxf(fmaxf(wmx[0], wmx[1]), fmaxf(wmx[2], wmx[3]));
            if (tid == 0) bmaxc[(size_t)i * NWG + wg] = bmax2;
            if (vc >= bmax2 - DELTA) {
                unsigned p = atomicAdd(&s_cnt, 1u);
                size_t slot = (size_t)i * NWG * CAPB + (size_t)wg * CAPB + p;
                cvals[slot] = vc; cidx[slot] = (unsigned)(NS + n);
            }
        }
        __syncthreads();
        if (tid == 0) cntc[(size_t)i * NWG + wg] = s_cnt;

        gbar(bar, i, wg);              // pushes of iter i globally visible

        if (i == ITERS - 1) break;

        // ---- phase B (redundant in every block; all compute identical mnL)
        {
            float g = fmaxf(bmaxp[tid], bmaxc[(size_t)i * NWG + tid]);  // tid<256==NWG
            for (int off = 32; off; off >>= 1) g = fmaxf(g, __shfl_xor(g, off));
            if (lane == 0) wmx[wid] = g;
        }
        if (tid == 0) s_fcnt = 0u;
        __syncthreads();
        const float gmax = fmaxf(fmaxf(wmx[0], wmx[1]), fmaxf(wmx[2], wmx[3]));
        const float thr = gmax - DELTA;
        // filter: thread t scans segment t (NWG==WGS)
        {
            unsigned c = cntp[tid];
            for (unsigned k = 0; k < c; ++k) {
                float val = pvals[tid * CAPB + k];
                if (val >= thr) {
                    unsigned p = atomicAdd(&s_fcnt, 1u);
                    if (p < SCAP) skey[p] = packkey(val, pidx[tid * CAPB + k]);
                }
            }
            c = cntc[(size_t)i * NWG + tid];
            const size_t sb = (size_t)i * NWG * CAPB + (size_t)tid * CAPB;
            for (unsigned k = 0; k < c; ++k) {
                float val = cvals[sb + k];
                if (val >= thr) {
                    unsigned p = atomicAdd(&s_fcnt, 1u);
                    if (p < SCAP) skey[p] = packkey(val, cidx[sb + k]);
                }
            }
        }
        __syncthreads();
        unsigned fc = s_fcnt; if (fc > SCAP) fc = SCAP;
        if (fc > 64u) {   // exact top-64 via bitonic on packed keys
            unsigned P2 = 128; while (P2 < fc) P2 <<= 1;
            for (unsigned k = fc + tid; k < P2; k += WGS) skey[k] = 0ull;
            __syncthreads();
            for (unsigned kk = 2; kk <= P2; kk <<= 1) {
                for (unsigned j = kk >> 1; j; j >>= 1) {
                    for (unsigned x = tid; x < P2; x += WGS) {
                        unsigned l = x ^ j;
                        if (l > x) {
                            unsigned long long k0 = skey[x], k1 = skey[l];
                            bool desc = ((x & kk) == 0);
                            if (desc ? (k0 < k1) : (k0 > k1)) { skey[x] = k1; skey[l] = k0; }
                        }
                    }
                    __syncthreads();
                }
            }
        }
        const int E = (fc < 64u) ? (int)fc : 64;
        if (tid < 64) {
            float we = (tid < E) ? expf(decf((unsigned)(skey[tid] >> 32)) - gmax) : 0.0f;
            w[tid] = we;
            float s = we;
            for (int off = 32; off; off >>= 1) s += __shfl_xor(s, off);
            if (tid == 0) s_S = s;
        }
        __syncthreads();
        const float invS = 1.0f / (s_S * (1.0f + 1e-9f));
        // gather elite actions: thread (e,a), batched 18 loads
        {
            const int e = tid >> 2, aa = tid & 3;
            float av[H];
            unsigned idx = (e < E) ? (unsigned)~(unsigned)(skey[e] & 0xFFFFFFFFull) : 0u;
            if (e < E) {
                if (idx < NS) {
#pragma unroll
                    for (int h = 0; h < H; ++h)
                        av[h] = pi[(size_t)h * NS * AD + (size_t)idx * AD + aa];
                } else {
                    const unsigned mm = idx - NS;
                    const float* nzi = noise + (size_t)i * H * NS * AD;
#pragma unroll
                    for (int h = 0; h < H; ++h)
                        av[h] = clamp4f(mnL[h*4+aa] + scale * nzi[(size_t)h * NS * AD + (size_t)mm * AD + aa]);
                }
            } else {
#pragma unroll
                for (int h = 0; h < H; ++h) av[h] = 0.0f;
            }
            const float we = (e < E) ? w[e] : 0.0f;
#pragma unroll
            for (int h = 0; h < H; ++h) buf[e * 73 + h * 4 + aa] = we * av[h];
        }
        __syncthreads();
        if (tid < H * AD) {
            float s = 0.f;
#pragma unroll 8
            for (int e = 0; e < 64; ++e) s += buf[e * 73 + tid];
            mnL[tid] = 0.1f * mnL[tid] + 0.9f * (s * invS);
        }
        __syncthreads();
        scale = 1.0f;
    }

    // ---- final: block 0 takes exact argmax over (pi-list ∪ cem5-list)
    if (wg == 0) {
        unsigned long long bk = 0ull;
        {
            unsigned c = cntp[tid];
            for (unsigned k = 0; k < c; ++k) {
                unsigned long long key = packkey(pvals[tid * CAPB + k], pidx[tid * CAPB + k]);
                if (key > bk) bk = key;
            }
            c = cntc[(size_t)5 * NWG + tid];
            const size_t sb = (size_t)5 * NWG * CAPB + (size_t)tid * CAPB;
            for (unsigned k = 0; k < c; ++k) {
                unsigned long long key = packkey(cvals[sb + k], cidx[sb + k]);
                if (key > bk) bk = key;
            }
        }
        for (int off = 32; off; off >>= 1) {
            unsigned long long ok = __shfl_xor(bk, off);
            if (ok > bk) bk = ok;
        }
        if (lane == 0) skey[wid] = bk;
        __syncthreads();
        if (tid == 0) {
            unsigned long long b0 = skey[0];
            for (int q = 1; q < 4; ++q) if (skey[q] > b0) b0 = skey[q];
            skey[0] = b0;
        }
        __syncthreads();
        const unsigned idx = (unsigned)~(unsigned)(skey[0] & 0xFFFFFFFFull);
        if (tid < H * AD) {
            const int h = tid >> 2, aa = tid & 3;
            float o;
            if (idx < NS) o = pi[(size_t)h * NS * AD + (size_t)idx * AD + aa];
            else o = clamp4f(mnL[tid] + 1.0f * noise[(size_t)5 * H * NS * AD + (size_t)h * NS * AD + (size_t)(idx - NS) * AD + aa]);
            out[tid] = o;
        }
    }
}

extern "C" void kernel_launch(void* const* d_in, const int* in_sizes, int n_in,
                              void* d_out, int out_size, void* d_ws, size_t ws_size,
                              hipStream_t stream) {
    const float* pi     = (const float*)d_in[0];
    const float* noise  = (const float*)d_in[1];
    const float* target = (const float*)d_in[2];
    float* out = (float*)d_out;

    unsigned* bar   = (unsigned*)d_ws;                        // 6*64 uints (memset)
    float* bmaxp    = (float*)(bar + 6 * 64);                 // NWG
    float* bmaxc    = bmaxp + NWG;                            // 6*NWG
    unsigned* cntp  = (unsigned*)(bmaxc + ITERS * NWG);       // NWG
    unsigned* cntc  = cntp + NWG;                             // 6*NWG
    float* pvals    = (float*)(cntc + ITERS * NWG);           // NWG*CAPB
    unsigned* pidx  = (unsigned*)(pvals + NWG * CAPB);        // NWG*CAPB
    float* cvals    = (float*)(pidx + NWG * CAPB);            // 6*NWG*CAPB
    unsigned* cidx  = (unsigned*)(cvals + (size_t)ITERS * NWG * CAPB);

    (void)hipMemsetAsync(bar, 0, 6 * 64 * sizeof(unsigned), stream);

    void* args[] = {(void*)&pi, (void*)&noise, (void*)&target, (void*)&out,
                    (void*)&bar, (void*)&bmaxp, (void*)&bmaxc, (void*)&cntp,
                    (void*)&cntc, (void*)&pvals, (void*)&pidx, (void*)&cvals,
                    (void*)&cidx};
    (void)hipLaunchCooperativeKernel((void*)k_mppi, dim3(NWG), dim3(WGS), args, 0, stream);
}

// Round 9
// 242.719 us; speedup vs baseline: 1.7130x; 1.4882x over previous
//
#include <hip/hip_runtime.h>
#include <math.h>

#define H 18
#define NS 65536
#define AD 4
#define ITERS 6
#define DELTA 16.0f
#define NWG 256
#define WGS 256
#define CAPB 256      // per-block segment capacity == WGS => cannot overflow
#define SCAP 1024

__device__ __forceinline__ unsigned encf(float f) {
    unsigned u = __float_as_uint(f);
    return (u & 0x80000000u) ? ~u : (u | 0x80000000u);
}
__device__ __forceinline__ float decf(unsigned u) {
    return __uint_as_float((u & 0x80000000u) ? (u & 0x7FFFFFFFu) : ~u);
}
__device__ __forceinline__ float clamp4f(float x) { return fminf(fmaxf(x, -4.0f), 4.0f); }
// descending u64 order == value desc, then index asc (matches top_k tie-break)
__device__ __forceinline__ unsigned long long packkey(float v, unsigned idx) {
    return ((unsigned long long)encf(v) << 32) | (unsigned long long)(~idx);
}

// One kernel per MPPI iteration. No global atomics anywhere; all cross-kernel
// state is plain-stored into block-owned slots and re-written every replay.
__global__ void __launch_bounds__(WGS) k_step(
        const float* __restrict__ pi, const float* __restrict__ noise,
        const float* __restrict__ target, float* __restrict__ meanarr,
        float* __restrict__ bmaxp, float* __restrict__ bmaxc,
        unsigned* __restrict__ cntp, unsigned* __restrict__ cntc,
        float* __restrict__ pvals, unsigned* __restrict__ pidx,
        float* __restrict__ cvals, unsigned* __restrict__ cidx, int iter) {
    __shared__ float tgt[H * AD], mnL[H * AD];
    __shared__ float wmx[4];
    __shared__ unsigned long long skey[SCAP];
    __shared__ float buf[64 * 73];
    __shared__ float w[64];
    __shared__ unsigned s_cnt, s_fcnt;
    __shared__ float s_S;

    const int tid = threadIdx.x;
    const int wg = blockIdx.x;
    const int lane = tid & 63;
    const int wid = tid >> 6;
    const int n = wg * WGS + tid;

    if (tid < H * AD) tgt[tid] = target[tid];
    if (tid == 0) { s_cnt = 0u; s_fcnt = 0u; }

    if (iter == 0) {
        if (tid < H * AD) {
            float m0 = pi[(size_t)(tid >> 2) * NS * AD + (tid & 3)];  // pi[:,0,:]
            mnL[tid] = m0;
            meanarr[tid] = m0;   // identical values from all blocks: benign
        }
        __syncthreads();
        // ---- pi candidate values (computed once, pushed to segments)
        const float4* pi4 = (const float4*)pi;
        float acc = 0.f;
#pragma unroll
        for (int h = 0; h < H; ++h) {
            float4 p = pi4[(size_t)h * NS + n];
            float c;
            c = p.x - tgt[h*4+0]; acc += c*c;
            c = p.y - tgt[h*4+1]; acc += c*c;
            c = p.z - tgt[h*4+2]; acc += c*c;
            c = p.w - tgt[h*4+3]; acc += c*c;
        }
        const float vpi = -acc;
        float m = vpi;
        for (int off = 32; off; off >>= 1) m = fmaxf(m, __shfl_xor(m, off));
        if (lane == 0) wmx[wid] = m;
        __syncthreads();
        const float bmax = fmaxf(fmaxf(wmx[0], wmx[1]), fmaxf(wmx[2], wmx[3]));
        if (tid == 0) bmaxp[wg] = bmax;
        if (vpi >= bmax - DELTA) {
            unsigned p = atomicAdd(&s_cnt, 1u);
            pvals[wg * CAPB + p] = vpi; pidx[wg * CAPB + p] = (unsigned)n;
        }
        __syncthreads();
        if (tid == 0) { cntp[wg] = s_cnt; s_cnt = 0u; }
        __syncthreads();
    } else {
        // ---- phase B for iter-1 (redundant in every block; identical results)
        if (tid < H * AD) mnL[tid] = meanarr[(size_t)(iter - 1) * H * AD + tid];
        __syncthreads();
        {
            float g = fmaxf(bmaxp[tid], bmaxc[(size_t)(iter - 1) * NWG + tid]);  // NWG==WGS
            for (int off = 32; off; off >>= 1) g = fmaxf(g, __shfl_xor(g, off));
            if (lane == 0) wmx[wid] = g;
        }
        __syncthreads();
        const float gmax = fmaxf(fmaxf(wmx[0], wmx[1]), fmaxf(wmx[2], wmx[3]));
        const float thr = gmax - DELTA;
        // filter: thread t scans segment t (NWG==WGS)
        {
            unsigned c = cntp[tid];
            for (unsigned k = 0; k < c; ++k) {
                float val = pvals[tid * CAPB + k];
                if (val >= thr) {
                    unsigned p = atomicAdd(&s_fcnt, 1u);
                    if (p < SCAP) skey[p] = packkey(val, pidx[tid * CAPB + k]);
                }
            }
            c = cntc[(size_t)(iter - 1) * NWG + tid];
            const size_t sb = (size_t)(iter - 1) * NWG * CAPB + (size_t)tid * CAPB;
            for (unsigned k = 0; k < c; ++k) {
                float val = cvals[sb + k];
                if (val >= thr) {
                    unsigned p = atomicAdd(&s_fcnt, 1u);
                    if (p < SCAP) skey[p] = packkey(val, cidx[sb + k]);
                }
            }
        }
        __syncthreads();
        unsigned fc = s_fcnt; if (fc > SCAP) fc = SCAP;
        if (fc > 64u) {   // exact top-64 via bitonic on packed keys
            unsigned P2 = 128; while (P2 < fc) P2 <<= 1;
            for (unsigned k = fc + tid; k < P2; k += WGS) skey[k] = 0ull;
            __syncthreads();
            for (unsigned kk = 2; kk <= P2; kk <<= 1) {
                for (unsigned j = kk >> 1; j; j >>= 1) {
                    for (unsigned x = tid; x < P2; x += WGS) {
                        unsigned l = x ^ j;
                        if (l > x) {
                            unsigned long long k0 = skey[x], k1 = skey[l];
                            bool desc = ((x & kk) == 0);
                            if (desc ? (k0 < k1) : (k0 > k1)) { skey[x] = k1; skey[l] = k0; }
                        }
                    }
                    __syncthreads();
                }
            }
        }
        const int E = (fc < 64u) ? (int)fc : 64;
        if (tid < 64) {
            float we = (tid < E) ? expf(decf((unsigned)(skey[tid] >> 32)) - gmax) : 0.0f;
            w[tid] = we;
            float s = we;
            for (int off = 32; off; off >>= 1) s += __shfl_xor(s, off);
            if (tid == 0) s_S = s;
        }
        __syncthreads();
        const float invS = 1.0f / (s_S * (1.0f + 1e-9f));
        // gather elite actions: thread (e,a), 18 batched independent loads
        {
            const float pscale = (iter - 1 == 0) ? 0.5f : 1.0f;
            const int e = tid >> 2, aa = tid & 3;
            float av[H];
            unsigned idx = (e < E) ? (unsigned)~(unsigned)(skey[e] & 0xFFFFFFFFull) : 0u;
            if (e < E) {
                if (idx < NS) {
#pragma unroll
                    for (int h = 0; h < H; ++h)
                        av[h] = pi[(size_t)h * NS * AD + (size_t)idx * AD + aa];
                } else {
                    const unsigned mm = idx - NS;
                    const float* nzi = noise + (size_t)(iter - 1) * H * NS * AD;
#pragma unroll
                    for (int h = 0; h < H; ++h)
                        av[h] = clamp4f(mnL[h*4+aa] + pscale * nzi[(size_t)h * NS * AD + (size_t)mm * AD + aa]);
                }
            } else {
#pragma unroll
                for (int h = 0; h < H; ++h) av[h] = 0.0f;
            }
            const float we = (e < E) ? w[e] : 0.0f;
#pragma unroll
            for (int h = 0; h < H; ++h) buf[e * 73 + h * 4 + aa] = we * av[h];
        }
        __syncthreads();
        if (tid < H * AD) {
            float s = 0.f;
#pragma unroll 8
            for (int e = 0; e < 64; ++e) s += buf[e * 73 + tid];
            float nm = 0.1f * mnL[tid] + 0.9f * (s * invS);
            mnL[tid] = nm;
            meanarr[(size_t)iter * H * AD + tid] = nm;
        }
        __syncthreads();
        if (tid == 0) s_cnt = 0u;
        __syncthreads();
    }

    // ---- phase A: cem values for this iteration
    const float scale = (iter == 0) ? 0.5f : 1.0f;
    const float4* nz4 = (const float4*)noise + (size_t)iter * H * NS;
    float a2 = 0.f;
#pragma unroll
    for (int h = 0; h < H; ++h) {
        float4 x = nz4[(size_t)h * NS + n];
        float c;
        c = clamp4f(mnL[h*4+0] + scale * x.x) - tgt[h*4+0]; a2 += c*c;
        c = clamp4f(mnL[h*4+1] + scale * x.y) - tgt[h*4+1]; a2 += c*c;
        c = clamp4f(mnL[h*4+2] + scale * x.z) - tgt[h*4+2]; a2 += c*c;
        c = clamp4f(mnL[h*4+3] + scale * x.w) - tgt[h*4+3]; a2 += c*c;
    }
    const float vc = -a2;
    float m2 = vc;
    for (int off = 32; off; off >>= 1) m2 = fmaxf(m2, __shfl_xor(m2, off));
    if (lane == 0) wmx[wid] = m2;
    __syncthreads();
    const float bmax2 = fmaxf(fmaxf(wmx[0], wmx[1]), fmaxf(wmx[2], wmx[3]));
    if (tid == 0) bmaxc[(size_t)iter * NWG + wg] = bmax2;
    if (vc >= bmax2 - DELTA) {
        unsigned p = atomicAdd(&s_cnt, 1u);
        size_t slot = (size_t)iter * NWG * CAPB + (size_t)wg * CAPB + p;
        cvals[slot] = vc; cidx[slot] = (unsigned)(NS + n);
    }
    __syncthreads();
    if (tid == 0) cntc[(size_t)iter * NWG + wg] = s_cnt;
}

// ---- final: one block, exact argmax over (pi-segments ∪ cem5-segments)
__global__ void __launch_bounds__(WGS) k_fin(
        const float* __restrict__ pi, const float* __restrict__ noise,
        const float* __restrict__ meanarr,
        const float* __restrict__ bmaxp, const float* __restrict__ bmaxc,
        const unsigned* __restrict__ cntp, const unsigned* __restrict__ cntc,
        const float* __restrict__ pvals, const unsigned* __restrict__ pidx,
        const float* __restrict__ cvals, const unsigned* __restrict__ cidx,
        float* __restrict__ out) {
    __shared__ float mnL[H * AD];
    __shared__ unsigned long long wk[4];
    const int tid = threadIdx.x, lane = tid & 63, wid = tid >> 6;
    if (tid < H * AD) mnL[tid] = meanarr[(size_t)5 * H * AD + tid];
    unsigned long long bk = 0ull;
    {
        unsigned c = cntp[tid];
        for (unsigned k = 0; k < c; ++k) {
            unsigned long long key = packkey(pvals[tid * CAPB + k], pidx[tid * CAPB + k]);
            if (key > bk) bk = key;
        }
        c = cntc[(size_t)5 * NWG + tid];
        const size_t sb = (size_t)5 * NWG * CAPB + (size_t)tid * CAPB;
        for (unsigned k = 0; k < c; ++k) {
            unsigned long long key = packkey(cvals[sb + k], cidx[sb + k]);
            if (key > bk) bk = key;
        }
    }
    for (int off = 32; off; off >>= 1) {
        unsigned long long ok = __shfl_xor(bk, off);
        if (ok > bk) bk = ok;
    }
    if (lane == 0) wk[wid] = bk;
    __syncthreads();
    if (tid == 0) {
        unsigned long long b0 = wk[0];
        for (int q = 1; q < 4; ++q) if (wk[q] > b0) b0 = wk[q];
        wk[0] = b0;
    }
    __syncthreads();
    const unsigned idx = (unsigned)~(unsigned)(wk[0] & 0xFFFFFFFFull);
    if (tid < H * AD) {
        const int h = tid >> 2, aa = tid & 3;
        float o;
        if (idx < NS) o = pi[(size_t)h * NS * AD + (size_t)idx * AD + aa];
        else o = clamp4f(mnL[tid] + 1.0f * noise[(size_t)5 * H * NS * AD + (size_t)h * NS * AD + (size_t)(idx - NS) * AD + aa]);
        out[tid] = o;
    }
}

extern "C" void kernel_launch(void* const* d_in, const int* in_sizes, int n_in,
                              void* d_out, int out_size, void* d_ws, size_t ws_size,
                              hipStream_t stream) {
    const float* pi     = (const float*)d_in[0];
    const float* noise  = (const float*)d_in[1];
    const float* target = (const float*)d_in[2];
    float* out = (float*)d_out;

    float* ws = (float*)d_ws;
    float* meanarr  = ws;                                     // 6*72 (pad 512)
    float* bmaxp    = meanarr + 512;                          // NWG
    float* bmaxc    = bmaxp + NWG;                            // 6*NWG
    unsigned* cntp  = (unsigned*)(bmaxc + ITERS * NWG);       // NWG
    unsigned* cntc  = cntp + NWG;                             // 6*NWG
    float* pvals    = (float*)(cntc + ITERS * NWG);           // NWG*CAPB
    unsigned* pidx  = (unsigned*)(pvals + NWG * CAPB);        // NWG*CAPB
    float* cvals    = (float*)(pidx + NWG * CAPB);            // 6*NWG*CAPB
    unsigned* cidx  = (unsigned*)(cvals + (size_t)ITERS * NWG * CAPB);

    for (int i = 0; i < ITERS; ++i)
        k_step<<<NWG, WGS, 0, stream>>>(pi, noise, target, meanarr, bmaxp, bmaxc,
                                        cntp, cntc, pvals, pidx, cvals, cidx, i);
    k_fin<<<1, WGS, 0, stream>>>(pi, noise, meanarr, bmaxp, bmaxc, cntp, cntc,
                                 pvals, pidx, cvals, cidx, out);
}